// Round 1
// baseline (186.873 us; speedup 1.0000x reference)
//
#include <hip/hip_runtime.h>
#include <hip/hip_bf16.h>

// ScaledDotProdAttn (no softmax): attn = (q@k^T)/8 ; out = attn@v
// B=32, SQ=SK=2048, D=64, fp32 in/out. d_out = [out (32*2048*64)] ++ [attn (32*2048*2048)]
// Fused single pass: per Q-block of 128 rows, iterate K-tiles of 128;
// compute S via bf16 MFMA, write S fp32 to attn (nontemporal), keep S bf16
// in LDS for the PV MFMA accumulation. attn is never re-read from HBM.

typedef __attribute__((ext_vector_type(4))) float  f32x4;
typedef __attribute__((ext_vector_type(8))) short  s16x8;

#define NB    32
#define SQL   2048
#define SKL   2048
#define DD    64
#define QBLK  128
#define KBLK  128
#define NTILES (SKL / KBLK)

// LDS layout (64 KB total -> 2 blocks/CU):
//   [0      ,16384) K tile   : 128 rows(key) x 64 bf16, stride 128 B, sw128
//   [16384  ,32768) V^T tile : 64 rows(d)   x 128 bf16, stride 256 B, sw256
//   [32768  ,65536) S tile   : 128 rows(q)  x 128 bf16, stride 256 B, sw256
//   (Q staged once into the S region with sw128, read to regs, then region reused)
#define KS_OFF 0
#define VT_OFF 16384
#define SS_OFF 32768

__device__ __forceinline__ unsigned short f2bf(float f) {
    union { float f; unsigned u; } x; x.f = f;
    unsigned r = x.u + 0x7FFFu + ((x.u >> 16) & 1u);   // RNE
    return (unsigned short)(r >> 16);
}

// XOR swizzles: keep 16B-aligned accesses 16B-aligned (bits 4..6 only).
__device__ __forceinline__ unsigned sw128(unsigned row, unsigned bc) {
    return row * 128u + (bc ^ ((row & 7u) << 4));
}
__device__ __forceinline__ unsigned sw256(unsigned row, unsigned bc) {
    return row * 256u + (bc ^ ((((row >> 3) ^ row) & 7u) << 4));
}

__global__ __launch_bounds__(256, 2)
void sdpa_fused(const float* __restrict__ qg, const float* __restrict__ kg,
                const float* __restrict__ vg, float* __restrict__ og,
                float* __restrict__ ag) {
    __shared__ __align__(16) char smem[65536];

    const unsigned tid  = threadIdx.x;
    const unsigned wid  = tid >> 6;
    const unsigned lane = tid & 63u;
    const unsigned l15  = lane & 15u;
    const unsigned l4   = lane >> 4;        // 0..3
    const unsigned b    = blockIdx.x >> 4;
    const unsigned qt   = blockIdx.x & 15u;
    const unsigned qbase = qt * QBLK;
    const unsigned wr = wid >> 1, wc = wid & 1u;   // 2x2 wave grid for S

    // ---- stage Q (prescaled by 1/8) into SS region, sw128 layout ----
    {
        const float* src = qg + (size_t)b * SQL * DD + (size_t)qbase * DD;
        const unsigned r0 = tid >> 3, c8 = tid & 7u;
        #pragma unroll
        for (int p = 0; p < 4; ++p) {
            unsigned row = p * 32 + r0;
            const float4* s = (const float4*)(src + row * DD + c8 * 8);
            float4 f0 = s[0], f1 = s[1];
            s16x8 h;
            h[0] = (short)f2bf(f0.x * 0.125f); h[1] = (short)f2bf(f0.y * 0.125f);
            h[2] = (short)f2bf(f0.z * 0.125f); h[3] = (short)f2bf(f0.w * 0.125f);
            h[4] = (short)f2bf(f1.x * 0.125f); h[5] = (short)f2bf(f1.y * 0.125f);
            h[6] = (short)f2bf(f1.z * 0.125f); h[7] = (short)f2bf(f1.w * 0.125f);
            *(s16x8*)(smem + SS_OFF + sw128(row, c8 * 16)) = h;
        }
    }
    __syncthreads();

    // Q fragments are loop-invariant: hold in registers for the whole kernel.
    s16x8 aq[4][2];
    #pragma unroll
    for (int m = 0; m < 4; ++m)
        #pragma unroll
        for (int ks = 0; ks < 2; ++ks)
            aq[m][ks] = *(const s16x8*)(smem + SS_OFF +
                        sw128(wr * 64 + m * 16 + l15, ks * 64 + l4 * 16));

    f32x4 acc_o[2][4];
    #pragma unroll
    for (int m = 0; m < 2; ++m)
        #pragma unroll
        for (int n = 0; n < 4; ++n)
            acc_o[m][n] = (f32x4){0.f, 0.f, 0.f, 0.f};

    const float* kbat = kg + (size_t)b * SKL * DD;
    const float* vbat = vg + (size_t)b * SKL * DD;

    for (int kt = 0; kt < NTILES; ++kt) {
        // ---- stage K tile (sw128) and V^T tile (sw256) ----
        {
            const float* ksrc = kbat + (size_t)kt * KBLK * DD;
            const float* vsrc = vbat + (size_t)kt * KBLK * DD;
            const unsigned r0 = tid >> 3, c8 = tid & 7u;
            #pragma unroll
            for (int p = 0; p < 4; ++p) {
                unsigned row = p * 32 + r0;
                const float4* s = (const float4*)(ksrc + row * DD + c8 * 8);
                float4 f0 = s[0], f1 = s[1];
                s16x8 h;
                h[0] = (short)f2bf(f0.x); h[1] = (short)f2bf(f0.y);
                h[2] = (short)f2bf(f0.z); h[3] = (short)f2bf(f0.w);
                h[4] = (short)f2bf(f1.x); h[5] = (short)f2bf(f1.y);
                h[6] = (short)f2bf(f1.z); h[7] = (short)f2bf(f1.w);
                *(s16x8*)(smem + KS_OFF + sw128(row, c8 * 16)) = h;

                const float4* sv = (const float4*)(vsrc + row * DD + c8 * 8);
                float4 g0 = sv[0], g1 = sv[1];
                float vv[8] = {g0.x, g0.y, g0.z, g0.w, g1.x, g1.y, g1.z, g1.w};
                #pragma unroll
                for (int j = 0; j < 8; ++j) {
                    unsigned d = c8 * 8 + (unsigned)j;       // 0..63
                    *(unsigned short*)(smem + VT_OFF + sw256(d, row * 2)) = f2bf(vv[j]);
                }
            }
        }
        __syncthreads();

        // ---- S = Q * K^T (scale folded into Q) ----
        f32x4 acc[4][4];
        #pragma unroll
        for (int m = 0; m < 4; ++m)
            #pragma unroll
            for (int n = 0; n < 4; ++n)
                acc[m][n] = (f32x4){0.f, 0.f, 0.f, 0.f};

        #pragma unroll
        for (int ks = 0; ks < 2; ++ks) {
            s16x8 bk[4];
            #pragma unroll
            for (int n = 0; n < 4; ++n)
                bk[n] = *(const s16x8*)(smem + KS_OFF +
                        sw128(wc * 64 + n * 16 + l15, ks * 64 + l4 * 16));
            #pragma unroll
            for (int m = 0; m < 4; ++m)
                #pragma unroll
                for (int n = 0; n < 4; ++n)
                    acc[m][n] = __builtin_amdgcn_mfma_f32_16x16x32_bf16(
                                    aq[m][ks], bk[n], acc[m][n], 0, 0, 0);
        }

        // ---- write attn (fp32, nontemporal) + S->bf16 into LDS ----
        float* ap = ag + (size_t)b * SQL * SKL
                       + (size_t)(qbase + wr * 64 + l4 * 4) * SKL
                       + (size_t)kt * KBLK + wc * 64 + l15;
        #pragma unroll
        for (int m = 0; m < 4; ++m) {
            #pragma unroll
            for (int n = 0; n < 4; ++n) {
                #pragma unroll
                for (int i = 0; i < 4; ++i) {
                    float val = acc[m][n][i];
                    __builtin_nontemporal_store(val, ap + (size_t)(m * 16 + i) * SKL + n * 16);
                    unsigned ql = wr * 64 + m * 16 + l4 * 4 + (unsigned)i;
                    unsigned kl = wc * 64 + n * 16 + l15;
                    *(unsigned short*)(smem + SS_OFF + sw256(ql, kl * 2)) = f2bf(val);
                }
            }
        }
        __syncthreads();

        // ---- O += S * V ---- (each wave: 32 q-rows x 64 d)
        #pragma unroll
        for (int ks = 0; ks < 4; ++ks) {
            s16x8 sa0 = *(const s16x8*)(smem + SS_OFF +
                        sw256(wid * 32 + l15,      ks * 64 + l4 * 16));
            s16x8 sa1 = *(const s16x8*)(smem + SS_OFF +
                        sw256(wid * 32 + 16 + l15, ks * 64 + l4 * 16));
            #pragma unroll
            for (int n = 0; n < 4; ++n) {
                s16x8 vb = *(const s16x8*)(smem + VT_OFF +
                           sw256(n * 16 + l15, ks * 64 + l4 * 16));
                acc_o[0][n] = __builtin_amdgcn_mfma_f32_16x16x32_bf16(sa0, vb, acc_o[0][n], 0, 0, 0);
                acc_o[1][n] = __builtin_amdgcn_mfma_f32_16x16x32_bf16(sa1, vb, acc_o[1][n], 0, 0, 0);
            }
        }
        __syncthreads();
    }

    // ---- write O ----
    float* op = og + (size_t)b * SQL * DD
                   + (size_t)(qbase + wid * 32 + l4 * 4) * DD + l15;
    #pragma unroll
    for (int m = 0; m < 2; ++m)
        #pragma unroll
        for (int n = 0; n < 4; ++n)
            #pragma unroll
            for (int i = 0; i < 4; ++i)
                __builtin_nontemporal_store(acc_o[m][n][i], op + (m * 16 + i) * DD + n * 16);
}

extern "C" void kernel_launch(void* const* d_in, const int* in_sizes, int n_in,
                              void* d_out, int out_size, void* d_ws, size_t ws_size,
                              hipStream_t stream) {
    const float* q = (const float*)d_in[0];
    const float* k = (const float*)d_in[1];
    const float* v = (const float*)d_in[2];
    float* outp  = (float*)d_out;                      // [32][2048][64]
    float* attnp = outp + (size_t)NB * SQL * DD;       // [32][2048][2048]
    sdpa_fused<<<dim3(NB * (SQL / QBLK)), dim3(256), 0, stream>>>(q, k, v, outp, attnp);
}